// Round 1
// 199.552 us; speedup vs baseline: 1.0104x; 1.0104x over previous
//
#include <hip/hip_runtime.h>
#include <math.h>

#define B_  64
#define T_  1024
#define QD_ 1024
#define CD_ 512
#define SEGROWS_ 16          // one combined partial row per seg-block
#define NBLK_ 16             // ctx blocks per batch; each covers 64 timesteps

// native vector type: __builtin_nontemporal_load requires scalar/ext-vector,
// not HIP_vector_type<float,4>
typedef float floatx4 __attribute__((ext_vector_type(4)));

// ---------------------------------------------------------------------------
// Kernel 1: fused alpha + context partials, prefetch-first.
// grid = (NBLK_=16, B), 256 threads. Changes vs previous version:
//  - alpha kept in registers (float4 + predicated scalar for t-1): removes
//    the s_alpha LDS round-trip and ONE full barrier (each barrier costs a
//    compiler-forced vmcnt(0) drain).
//  - first 8 input rows are prefetched BEFORE the powf/reduce prologue, so
//    HBM streaming starts immediately and the prologue hides under latency.
//  - the two 32-timestep halves are combined in-block through 2 KB of LDS:
//    part shrinks 4 MB -> 2 MB (write) and kernel 2's fetch halves too.
// ---------------------------------------------------------------------------
__global__ __launch_bounds__(256) void attn_ctx_all(
    const float* __restrict__ inputs, const float* __restrict__ alpha,
    const float* __restrict__ u, const float* __restrict__ sq,
    float* __restrict__ part, float* __restrict__ out_a)
{
    const int seg = blockIdx.x;      // 0..15
    const int b   = blockIdx.y;
    const int tid = threadIdx.x;     // 0..255

    __shared__ float  s_seg[64];     // raw[] for this block's 64 timesteps
    __shared__ float  s_red[4];
    __shared__ float4 s_comb[128];   // half-1 partial for in-block combine

    const int lane  = tid & 127;     // float4 channel of CD
    const int half  = tid >> 7;      // 0/1
    const int tbase = seg * 64 + half * 32;
    const floatx4* in4 =
        (const floatx4*)(inputs + ((size_t)b * T_ + tbase) * CD_);

    // ---- issue alpha/u/sq loads first (oldest in vmcnt queue) ----
    const int t0 = tid * 4;
    const float4 a4   = ((const float4*)(alpha + (size_t)b * T_))[tid];
    const float aprev = (tid == 0) ? 0.f : alpha[(size_t)b * T_ + t0 - 1];
    const float ub    = u[b];
    const float sqb   = sq[b];

    // ---- prefetch first 8 input rows; they return while we do the powf row
    floatx4 xf[8];
#pragma unroll
    for (int i = 0; i < 8; ++i)
        xf[i] = __builtin_nontemporal_load(&in4[(size_t)i * 128 + lane]);

    // ---- raw row + local sum (thread owns t in [4*tid, 4*tid+4)) ----
    const float omu = 1.0f - ub;
    float rr[4];
    float lsum;
    {
        const float x0 = omu * a4.x + ub * aprev + 1e-6f;
        const float x1 = omu * a4.y + ub * a4.x  + 1e-6f;
        const float x2 = omu * a4.z + ub * a4.y  + 1e-6f;
        const float x3 = omu * a4.w + ub * a4.z  + 1e-6f;
        rr[0] = __powf(x0, sqb);
        rr[1] = __powf(x1, sqb);
        rr[2] = __powf(x2, sqb);
        rr[3] = __powf(x3, sqb);
        lsum = (rr[0] + rr[1]) + (rr[2] + rr[3]);
    }

    // segment owners stash their 64 raw values (16 threads, one wave)
    if ((tid >> 4) == seg) {
        const int o = t0 - seg * 64;
        s_seg[o + 0] = rr[0]; s_seg[o + 1] = rr[1];
        s_seg[o + 2] = rr[2]; s_seg[o + 3] = rr[3];
    }

    // block reduce (4 waves)
#pragma unroll
    for (int off = 32; off > 0; off >>= 1) lsum += __shfl_down(lsum, off);
    if ((tid & 63) == 0) s_red[tid >> 6] = lsum;
    __syncthreads();                             // covers s_seg + s_red
    const float inv = 1.0f / (s_red[0] + s_red[1] + s_red[2] + s_red[3]);

    // ---- segment dot: half h owns timesteps [seg*64 + h*32, +32) ----
    float4 acc = {0.f, 0.f, 0.f, 0.f};
#pragma unroll
    for (int i = 0; i < 32; ++i) {
        const floatx4 x = xf[i & 7];
        if (i + 8 < 32)
            xf[i & 7] = __builtin_nontemporal_load(&in4[(size_t)(i + 8) * 128 + lane]);
        const float av = s_seg[half * 32 + i];   // wave-uniform broadcast
        acc.x += av * x.x; acc.y += av * x.y;
        acc.z += av * x.z; acc.w += av * x.w;
    }

    // seg 0 writes the normalized attention weights (1 float4 per thread)
    if (seg == 0) {
        float4 o;
        o.x = rr[0] * inv; o.y = rr[1] * inv; o.z = rr[2] * inv; o.w = rr[3] * inv;
        ((float4*)(out_a + (size_t)b * T_))[tid] = o;
    }

    // ---- combine halves in-block: one partial row per seg ----
    if (half == 1) s_comb[lane] = acc;
    __syncthreads();
    if (half == 0) {
        const float4 o2 = s_comb[lane];
        float4 w;
        w.x = (acc.x + o2.x) * inv; w.y = (acc.y + o2.y) * inv;
        w.z = (acc.z + o2.z) * inv; w.w = (acc.w + o2.w) * inv;
        ((float4*)(part + ((size_t)b * SEGROWS_ + seg) * CD_))[lane] = w;
    }
}

// ---------------------------------------------------------------------------
// Kernel 2: reduce partials -> context; two 1536-element sigmoid heads.
// One block per batch, 512 threads (thread == context channel).
// ---------------------------------------------------------------------------
__global__ __launch_bounds__(512) void attn_final(
    const float* __restrict__ part,
    const float* __restrict__ query,
    const float* __restrict__ W_u, const float* __restrict__ b_u,
    const float* __restrict__ W_sq, const float* __restrict__ b_sq,
    float* __restrict__ out_ctx, float* __restrict__ out_u,
    float* __restrict__ out_sq)
{
    const int b   = blockIdx.x;
    const int tid = threadIdx.x;   // 0..511 == context channel

    float c = 0.f;
    const float* pb = part + (size_t)b * SEGROWS_ * CD_;
#pragma unroll
    for (int s = 0; s < SEGROWS_; ++s) c += pb[(size_t)s * CD_ + tid];
    out_ctx[(size_t)b * CD_ + tid] = c;

    const float* qb = query + (size_t)b * QD_;
    const float q0 = qb[tid];
    const float q1 = qb[tid + 512];

    float du = c * W_u[tid]  + q0 * W_u[512 + tid]  + q1 * W_u[1024 + tid];
    float ds = c * W_sq[tid] + q0 * W_sq[512 + tid] + q1 * W_sq[1024 + tid];
#pragma unroll
    for (int off = 32; off > 0; off >>= 1) {
        du += __shfl_down(du, off);
        ds += __shfl_down(ds, off);
    }
    __shared__ float s_u[8], s_s[8];
    if ((tid & 63) == 0) { s_u[tid >> 6] = du; s_s[tid >> 6] = ds; }
    __syncthreads();
    if (tid == 0) {
        float su = b_u[0], ss = b_sq[0];
#pragma unroll
        for (int w = 0; w < 8; ++w) { su += s_u[w]; ss += s_s[w]; }
        out_u[b]  = 1.0f / (1.0f + __expf(-su));
        out_sq[b] = 1.0f / (1.0f + __expf(-ss)) + 1.0f;
    }
}

// ---------------------------------------------------------------------------
// Fallback (ws too small — not expected, ws ~512 MB): atomics + heads.
// ---------------------------------------------------------------------------
__global__ __launch_bounds__(256) void attn_ctx_atomic(
    const float* __restrict__ inputs, const float* __restrict__ alpha,
    const float* __restrict__ u, const float* __restrict__ sq,
    float* __restrict__ ctx, float* __restrict__ out_a)
{
    const int seg = blockIdx.x;
    const int b   = blockIdx.y;
    const int tid = threadIdx.x;

    __shared__ float s_alpha[T_];
    __shared__ float s_raw[T_];
    __shared__ float s_red[4];

    ((float4*)s_alpha)[tid] = ((const float4*)(alpha + (size_t)b * T_))[tid];
    __syncthreads();

    const float ub  = u[b];
    const float sqb = sq[b];
    const float omu = 1.0f - ub;

    float lsum = 0.f;
    float rr[4];
    const int t0 = tid * 4;
#pragma unroll
    for (int i = 0; i < 4; ++i) {
        const int t = t0 + i;
        const float prev = (t == 0) ? 0.f : s_alpha[t - 1];
        const float x = omu * s_alpha[t] + ub * prev + 1e-6f;
        const float r = __powf(x, sqb);
        rr[i] = r; lsum += r;
    }
    {
        float4 w; w.x = rr[0]; w.y = rr[1]; w.z = rr[2]; w.w = rr[3];
        ((float4*)s_raw)[tid] = w;
    }
#pragma unroll
    for (int off = 32; off > 0; off >>= 1) lsum += __shfl_down(lsum, off);
    if ((tid & 63) == 0) s_red[tid >> 6] = lsum;
    __syncthreads();
    const float inv = 1.0f / (s_red[0] + s_red[1] + s_red[2] + s_red[3]);

    const int lane  = tid & 127;
    const int half  = tid >> 7;
    const int tbase = seg * 64 + half * 32;

    const float4* in4 =
        (const float4*)(inputs + ((size_t)b * T_ + tbase) * CD_);
    float4 acc = {0.f, 0.f, 0.f, 0.f};
    for (int i = 0; i < 32; ++i) {
        const float av = s_raw[tbase + i];
        const float4 x = in4[(size_t)i * 128 + lane];
        acc.x += av * x.x; acc.y += av * x.y; acc.z += av * x.z; acc.w += av * x.w;
    }
    float* dst = ctx + (size_t)b * CD_ + lane * 4;
    atomicAdd(dst + 0, acc.x * inv);
    atomicAdd(dst + 1, acc.y * inv);
    atomicAdd(dst + 2, acc.z * inv);
    atomicAdd(dst + 3, acc.w * inv);

    if (seg == 0) {
        float4 o;
        o.x = rr[0] * inv; o.y = rr[1] * inv; o.z = rr[2] * inv; o.w = rr[3] * inv;
        ((float4*)(out_a + (size_t)b * T_))[tid] = o;
    }
}

__global__ __launch_bounds__(512) void attn_heads(
    const float* __restrict__ query,
    const float* __restrict__ W_u, const float* __restrict__ b_u,
    const float* __restrict__ W_sq, const float* __restrict__ b_sq,
    const float* __restrict__ out_ctx, float* __restrict__ out_u,
    float* __restrict__ out_sq)
{
    const int b   = blockIdx.x;
    const int tid = threadIdx.x;

    const float c  = out_ctx[(size_t)b * CD_ + tid];
    const float* qb = query + (size_t)b * QD_;
    const float q0 = qb[tid];
    const float q1 = qb[tid + 512];

    float du = c * W_u[tid]  + q0 * W_u[512 + tid]  + q1 * W_u[1024 + tid];
    float ds = c * W_sq[tid] + q0 * W_sq[512 + tid] + q1 * W_sq[1024 + tid];
#pragma unroll
    for (int off = 32; off > 0; off >>= 1) {
        du += __shfl_down(du, off);
        ds += __shfl_down(ds, off);
    }
    __shared__ float s_u[8], s_s[8];
    if ((tid & 63) == 0) { s_u[tid >> 6] = du; s_s[tid >> 6] = ds; }
    __syncthreads();
    if (tid == 0) {
        float su = b_u[0], ss = b_sq[0];
#pragma unroll
        for (int w = 0; w < 8; ++w) { su += s_u[w]; ss += s_s[w]; }
        out_u[b]  = 1.0f / (1.0f + __expf(-su));
        out_sq[b] = 1.0f / (1.0f + __expf(-ss)) + 1.0f;
    }
}

// ---------------------------------------------------------------------------
extern "C" void kernel_launch(void* const* d_in, const int* in_sizes, int n_in,
                              void* d_out, int out_size, void* d_ws, size_t ws_size,
                              hipStream_t stream) {
    const float* query  = (const float*)d_in[0];  // [B,1,QD]
    const float* inputs = (const float*)d_in[1];  // [B,T,CD]
    const float* alpha  = (const float*)d_in[2];  // [B,T]
    const float* u      = (const float*)d_in[3];  // [B,1]
    const float* sq     = (const float*)d_in[4];  // [B,1]
    const float* W_u    = (const float*)d_in[5];  // [QD+CD,1]
    const float* b_u    = (const float*)d_in[6];  // [1]
    const float* W_sq   = (const float*)d_in[7];  // [QD+CD,1]
    const float* b_sq   = (const float*)d_in[8];  // [1]

    float* out      = (float*)d_out;
    float* out_ctx  = out;                         // [B,CD]
    float* out_a    = out + (size_t)B_ * CD_;      // [B,T]
    float* out_u    = out_a + (size_t)B_ * T_;     // [B]
    float* out_sq   = out_u + B_;                  // [B]

    const size_t part_bytes = (size_t)B_ * SEGROWS_ * CD_ * sizeof(float);

    if (ws_size >= part_bytes) {
        float* part = (float*)d_ws;
        attn_ctx_all<<<dim3(NBLK_, B_), 256, 0, stream>>>(
            inputs, alpha, u, sq, part, out_a);
        attn_final<<<B_, 512, 0, stream>>>(
            part, query, W_u, b_u, W_sq, b_sq, out_ctx, out_u, out_sq);
    } else {
        (void)hipMemsetAsync(out_ctx, 0, (size_t)B_ * CD_ * sizeof(float), stream);
        attn_ctx_atomic<<<dim3(NBLK_, B_), 256, 0, stream>>>(
            inputs, alpha, u, sq, out_ctx, out_a);
        attn_heads<<<B_, 512, 0, stream>>>(
            query, W_u, b_u, W_sq, b_sq, out_ctx, out_u, out_sq);
    }
}